// Round 1
// baseline (176.676 us; speedup 1.0000x reference)
//
#include <hip/hip_runtime.h>

#define N 512
#define TOPK 153
#define KP 160
#define D 64
#define NB 32          // batches
#define BN (NB*N)
#define EPSF 1e-8f

// ---------------- ws layout (bytes) ----------------
// 0x000000: cos/common f32[N*N]  (1MB)   (common overwrites cos after topk)
// 0x100000: G    u64[N*8]        (32KB)  gated selection bitmask (target-major)
// 0x108000: nb   u64[N*8]        (32KB)  symmetrized adjacency + self
// 0x110000: idxl i32[N*KP]       (320KB) top-k source ids per target (rank order)
// 0x160000: wgtl f32[N*KP]       (320KB) per-edge normalized weights
// 0x1B0000: dinv f32[N]
// 0x1B0800: norms f32[N]
// 0x1B1000: maxc i32
// 0x1C0000: h    f32[BN*D]       (4MB)
// total ~5.75MB

__global__ void k_norms(const float* __restrict__ emb, float* __restrict__ norms,
                        int* __restrict__ maxc) {
    int i = threadIdx.x;
    if (i == 0) *maxc = 0;
    if (i < N) {
        double s = 0.0;
        for (int d = 0; d < D; ++d) { double v = emb[i*D+d]; s += v*v; }
        norms[i] = (float)sqrt(s);
    }
}

__global__ void k_cos(const float* __restrict__ emb, const float* __restrict__ norms,
                      float* __restrict__ cosm) {
    __shared__ float er[D];
    int i = blockIdx.x, t = threadIdx.x;
    if (t < D) er[t] = emb[i*D+t];
    __syncthreads();
    float ni = norms[i];
    for (int j = t; j < N; j += 256) {
        double dot = 0.0;
        #pragma unroll 8
        for (int d = 0; d < D; ++d) dot += (double)er[d] * (double)emb[j*D+d];
        cosm[i*N+j] = (float)dot / (ni*norms[j] + EPSF);
    }
}

__global__ void k_topk(const float* __restrict__ cosm, int* __restrict__ idxl,
                       unsigned long long* __restrict__ G) {
    __shared__ float sr[N];
    __shared__ unsigned long long gb[8];
    int i = blockIdx.x, t = threadIdx.x;
    sr[t] = cosm[i*N+t]; sr[t+256] = cosm[i*N+t+256];
    if (t < 8) gb[t] = 0ull;
    __syncthreads();
    for (int jj = t; jj < N; jj += 256) {
        float v = sr[jj];
        int rank = 0;
        #pragma unroll 8
        for (int m = 0; m < N; ++m) {
            float u = sr[m];
            rank += (u > v) || (u == v && m < jj);   // jax.lax.top_k tie semantics
        }
        if (rank < TOPK) {
            idxl[i*KP + rank] = jj;                  // rank order == reference order
            atomicOr(&gb[jj>>6], 1ull << (jj&63));
        }
    }
    __syncthreads();
    if (t < 8) G[i*8+t] = gb[t];
}

__global__ void k_nb(const unsigned long long* __restrict__ G,
                     unsigned long long* __restrict__ nbm) {
    int tid = blockIdx.x*256 + threadIdx.x;   // 4096 total
    int a = tid >> 3, w = tid & 7;
    unsigned long long x = G[a*8+w];          // edges where a is target
    int aw = a >> 6, ab = a & 63;
    for (int bit = 0; bit < 64; ++bit) {      // transpose: edges where a is source
        int b = (w<<6) | bit;
        x |= ((G[b*8 + aw] >> ab) & 1ull) << bit;
    }
    if (aw == w) x |= 1ull << ab;             // self loop (nb = adj | I)
    nbm[a*8+w] = x;
}

__global__ void k_common(const unsigned long long* __restrict__ nbm,
                         float* __restrict__ common, int* __restrict__ maxc) {
    __shared__ unsigned long long ni[8];
    __shared__ int bmax;
    int i = blockIdx.x, t = threadIdx.x;
    if (t < 8) ni[t] = nbm[i*8+t];
    if (t == 0) bmax = 0;
    __syncthreads();
    int lm = 0;
    for (int j = t; j < N; j += 256) {
        int c = 0;
        #pragma unroll
        for (int w = 0; w < 8; ++w) c += __popcll(ni[w] & nbm[j*8+w]);
        common[i*N+j] = (float)c;
        lm = lm > c ? lm : c;
    }
    atomicMax(&bmax, lm);
    __syncthreads();
    if (t == 0) atomicMax(maxc, bmax);
}

__global__ void k_deg(const float* __restrict__ common, const int* __restrict__ idxl,
                      const int* __restrict__ maxc, float* __restrict__ dinv) {
    int i = blockIdx.x*256 + threadIdx.x;     // grid 2 -> 512
    float mc = (float)(*maxc);
    float deg = 0.f;
    for (int k = 0; k < TOPK; ++k) {
        int j = idxl[i*KP+k];
        float c = common[i*N+j];
        float ew = (c > 1.f) ? (c/mc)*c : 0.f;
        deg += ew;
    }
    dinv[i] = (deg > 0.f) ? (float)(1.0/sqrt((double)deg)) : 0.f;
}

__global__ void k_wgt(const float* __restrict__ common, const int* __restrict__ idxl,
                      const float* __restrict__ dinv, const int* __restrict__ maxc,
                      float* __restrict__ wgtl) {
    int tid = blockIdx.x*256 + threadIdx.x;   // 512*KP -> grid 320
    int i = tid / KP, k = tid % KP;
    if (k >= TOPK) return;
    float mc = (float)(*maxc);
    int j = idxl[i*KP+k];
    float c = common[i*N+j];
    float ew = (c > 1.f) ? (c/mc)*c : 0.f;
    wgtl[i*KP+k] = dinv[j]*ew*dinv[i];        // dinv[row]*ew*dinv[col]
}

__global__ void k_h(const float* __restrict__ x, const float* __restrict__ W,
                    float* __restrict__ h) {
    __shared__ float xs[16*64];
    __shared__ float Ws[64*64];
    int t = threadIdx.x; int r0 = blockIdx.x*16;
    ((float4*)xs)[t] = ((const float4*)(x + r0*64))[t];
    for (int e = t; e < 1024; e += 256) ((float4*)Ws)[e] = ((const float4*)W)[e];
    __syncthreads();
    int row = t >> 4, f0 = (t & 15)*4;
    float ax=0, ay=0, az=0, aw=0;
    #pragma unroll 8
    for (int c = 0; c < 64; ++c) {
        float xv = xs[row*64+c];
        float4 wv = *(const float4*)&Ws[c*64+f0];
        ax += xv*wv.x; ay += xv*wv.y; az += xv*wv.z; aw += xv*wv.w;
    }
    float4 o; o.x=ax; o.y=ay; o.z=az; o.w=aw;
    ((float4*)(h + r0*64))[t] = o;
}

__global__ __launch_bounds__(512)
void k_agg(const float* __restrict__ h, const int* __restrict__ idxl,
           const float* __restrict__ wgtl, const float* __restrict__ bias,
           float* __restrict__ out) {
    __shared__ float4 hs4[512*16];   // 128KB: h[b] staged
    __shared__ uint2  iw[32*80];     // 20KB: (idx, weight) pairs for 32 targets
    int chunk = blockIdx.x, b = blockIdx.y, t = threadIdx.x;
    const float4* hb = (const float4*)h + b*8192;
    for (int e = t; e < 8192; e += 512) hs4[e] = hb[e];
    int lane = t & 63, wv = t >> 6;
    int ts = lane >> 4, fq = lane & 15;
    int tl = wv*4 + ts;              // local target 0..31
    float4 bv = ((const float4*)bias)[fq];
    int i0 = chunk*64;
    for (int grp = 0; grp < 2; ++grp) {
        int tbase = i0 + grp*32;
        int ti = tbase + tl;
        float ax=0, ay=0, az=0, aw=0;
        for (int ph = 0; ph < 2; ++ph) {
            int k0 = ph*80;
            __syncthreads();         // protect iw overwrite vs prior reads
            for (int e = t; e < 32*80; e += 512) {
                int l = e/80, kk = e%80; int kg = k0 + kk;
                uint2 v;
                if (kg < TOPK) {
                    v.x = (unsigned)idxl[(tbase+l)*KP + kg];
                    v.y = __float_as_uint(wgtl[(tbase+l)*KP + kg]);
                } else { v.x = 0u; v.y = 0u; }   // zero-weight pad
                iw[e] = v;
            }
            __syncthreads();
            const uint2* ip = &iw[tl*80];
            #pragma unroll 4
            for (int kk = 0; kk < 80; ++kk) {
                uint2 p = ip[kk];
                float w = __uint_as_float(p.y);
                float4 hv = hs4[p.x*16 + fq];
                ax += w*hv.x; ay += w*hv.y; az += w*hv.z; aw += w*hv.w;
            }
        }
        float4 o; o.x = ax+bv.x; o.y = ay+bv.y; o.z = az+bv.z; o.w = aw+bv.w;
        ((float4*)out)[(b*512 + ti)*16 + fq] = o;
    }
}

extern "C" void kernel_launch(void* const* d_in, const int* in_sizes, int n_in,
                              void* d_out, int out_size, void* d_ws, size_t ws_size,
                              hipStream_t stream) {
    const float* x    = (const float*)d_in[0];   // [32,512,64]
    const float* W    = (const float*)d_in[1];   // [64,64]
    const float* bias = (const float*)d_in[2];   // [64]
    const float* emb  = (const float*)d_in[3];   // [512,64]
    float* out = (float*)d_out;

    char* ws = (char*)d_ws;
    float* cosm  = (float*)(ws + 0x000000);      // aliased: common after topk
    unsigned long long* G  = (unsigned long long*)(ws + 0x100000);
    unsigned long long* nbm = (unsigned long long*)(ws + 0x108000);
    int*   idxl  = (int*)(ws + 0x110000);
    float* wgtl  = (float*)(ws + 0x160000);
    float* dinv  = (float*)(ws + 0x1B0000);
    float* norms = (float*)(ws + 0x1B0800);
    int*   maxc  = (int*)(ws + 0x1B1000);
    float* h     = (float*)(ws + 0x1C0000);
    float* common = cosm;

    k_norms<<<1, 512, 0, stream>>>(emb, norms, maxc);
    k_cos<<<N, 256, 0, stream>>>(emb, norms, cosm);
    k_topk<<<N, 256, 0, stream>>>(cosm, idxl, G);
    k_nb<<<16, 256, 0, stream>>>(G, nbm);
    k_common<<<N, 256, 0, stream>>>(nbm, common, maxc);
    k_deg<<<2, 256, 0, stream>>>(common, idxl, maxc, dinv);
    k_wgt<<<320, 256, 0, stream>>>(common, idxl, dinv, maxc, wgtl);
    k_h<<<BN/16, 256, 0, stream>>>(x, W, h);
    k_agg<<<dim3(8, NB), 512, 0, stream>>>(h, idxl, wgtl, bias, out);
}

// Round 2
// 105.271 us; speedup vs baseline: 1.6783x; 1.6783x over previous
//
#include <hip/hip_runtime.h>

#define N 512
#define TOPK 153
#define KP 160
#define D 64
#define NB 32          // batches
#define BN (NB*N)
#define EPSF 1e-8f

// ---------------- ws layout (bytes) ----------------
// 0x000000: cos/common f32[N*N]  (1MB)   (common overwrites cos after topk)
// 0x100000: G    u64[N*8]        (32KB)  gated selection bitmask (target-major)
// 0x108000: nb   u64[N*8]        (32KB)  symmetrized adjacency + self
// 0x110000: idxl i32[N*KP]       (320KB) top-k source ids per target (rank order)
// 0x160000: wgtl f32[N*KP]       (320KB) raw ew, then normalized weights (in-place)
// 0x1B0000: dinv f32[N]
// 0x1B0800: norms f32[N]
// 0x1B1000: maxc i32
// 0x1C0000: h    f32[BN*D]       (4MB)
// total ~5.75MB

__global__ void k_norms(const float* __restrict__ emb, float* __restrict__ norms,
                        int* __restrict__ maxc) {
    int i = threadIdx.x;
    if (i == 0) *maxc = 0;
    if (i < N) {
        double s = 0.0;
        for (int d = 0; d < D; ++d) { double v = emb[i*D+d]; s += v*v; }
        norms[i] = (float)sqrt(s);
    }
}

__global__ void k_cos(const float* __restrict__ emb, const float* __restrict__ norms,
                      float* __restrict__ cosm) {
    __shared__ float er[D];
    int i = blockIdx.x, t = threadIdx.x;
    if (t < D) er[t] = emb[i*D+t];
    __syncthreads();
    float ni = norms[i];
    for (int j = t; j < N; j += 256) {
        double dot = 0.0;
        #pragma unroll 8
        for (int d = 0; d < D; ++d) dot += (double)er[d] * (double)emb[j*D+d];
        cosm[i*N+j] = (float)dot / (ni*norms[j] + EPSF);
    }
}

__global__ void k_topk(const float* __restrict__ cosm, int* __restrict__ idxl,
                       unsigned long long* __restrict__ G) {
    __shared__ float sr[N];
    __shared__ unsigned long long gb[8];
    int i = blockIdx.x, t = threadIdx.x;
    sr[t] = cosm[i*N+t]; sr[t+256] = cosm[i*N+t+256];
    if (t < 8) gb[t] = 0ull;
    __syncthreads();
    for (int jj = t; jj < N; jj += 256) {
        float v = sr[jj];
        int rank = 0;
        #pragma unroll 8
        for (int m = 0; m < N; ++m) {
            float u = sr[m];
            rank += (u > v) || (u == v && m < jj);   // jax.lax.top_k tie semantics
        }
        if (rank < TOPK) {
            idxl[i*KP + rank] = jj;                  // rank order == reference order
            atomicOr(&gb[jj>>6], 1ull << (jj&63));
        }
    }
    __syncthreads();
    if (t < 8) G[i*8+t] = gb[t];
}

__global__ void k_nb(const unsigned long long* __restrict__ G,
                     unsigned long long* __restrict__ nbm) {
    int tid = blockIdx.x*256 + threadIdx.x;   // 4096 total
    int a = tid >> 3, w = tid & 7;
    unsigned long long x = G[a*8+w];          // edges where a is target
    int aw = a >> 6, ab = a & 63;
    for (int bit = 0; bit < 64; ++bit) {      // transpose: edges where a is source
        int b = (w<<6) | bit;
        x |= ((G[b*8 + aw] >> ab) & 1ull) << bit;
    }
    if (aw == w) x |= 1ull << ab;             // self loop (nb = adj | I)
    nbm[a*8+w] = x;
}

__global__ void k_common(const unsigned long long* __restrict__ nbm,
                         float* __restrict__ common, int* __restrict__ maxc) {
    __shared__ unsigned long long ni[8];
    __shared__ int bmax;
    int i = blockIdx.x, t = threadIdx.x;
    if (t < 8) ni[t] = nbm[i*8+t];
    if (t == 0) bmax = 0;
    __syncthreads();
    int lm = 0;
    for (int j = t; j < N; j += 256) {
        int c = 0;
        #pragma unroll
        for (int w = 0; w < 8; ++w) c += __popcll(ni[w] & nbm[j*8+w]);
        common[i*N+j] = (float)c;
        lm = lm > c ? lm : c;
    }
    atomicMax(&bmax, lm);
    __syncthreads();
    if (t == 0) atomicMax(maxc, bmax);
}

// per-edge structural coeff + per-node degree, fully parallel
// (replaces the latency-bound serial k_deg: 76us -> ~2us)
__global__ void k_ew(const float* __restrict__ common, const int* __restrict__ idxl,
                     const int* __restrict__ maxc, float* __restrict__ wgtl,
                     float* __restrict__ dinv) {
    __shared__ float red[4];
    int i = blockIdx.x, k = threadIdx.x;
    float mc = (float)(*maxc);
    float ew = 0.f;
    if (k < TOPK) {
        int j = idxl[i*KP+k];
        float c = common[i*N+j];
        ew = (c > 1.f) ? (c/mc)*c : 0.f;
        wgtl[i*KP+k] = ew;                    // raw ew; scaled in k_wgt2
    }
    float s = ew;
    #pragma unroll
    for (int o = 32; o > 0; o >>= 1) s += __shfl_down(s, o, 64);
    if ((k & 63) == 0) red[k>>6] = s;
    __syncthreads();
    if (k == 0) {
        float deg = red[0]+red[1]+red[2]+red[3];
        dinv[i] = (deg > 0.f) ? (float)(1.0/sqrt((double)deg)) : 0.f;
    }
}

__global__ void k_wgt2(const int* __restrict__ idxl, const float* __restrict__ dinv,
                       float* __restrict__ wgtl) {
    int tid = blockIdx.x*256 + threadIdx.x;   // 512*KP -> grid 320
    int i = tid / KP, k = tid % KP;
    if (k >= TOPK) return;
    int j = idxl[i*KP+k];
    wgtl[i*KP+k] *= dinv[j]*dinv[i];          // dinv[row]*ew*dinv[col]
}

__global__ void k_h(const float* __restrict__ x, const float* __restrict__ W,
                    float* __restrict__ h) {
    __shared__ float xs[16*64];
    __shared__ float Ws[64*64];
    int t = threadIdx.x; int r0 = blockIdx.x*16;
    ((float4*)xs)[t] = ((const float4*)(x + r0*64))[t];
    for (int e = t; e < 1024; e += 256) ((float4*)Ws)[e] = ((const float4*)W)[e];
    __syncthreads();
    int row = t >> 4, f0 = (t & 15)*4;
    float ax=0, ay=0, az=0, aw=0;
    #pragma unroll 8
    for (int c = 0; c < 64; ++c) {
        float xv = xs[row*64+c];
        float4 wv = *(const float4*)&Ws[c*64+f0];
        ax += xv*wv.x; ay += xv*wv.y; az += xv*wv.z; aw += xv*wv.w;
    }
    float4 o; o.x=ax; o.y=ay; o.z=az; o.w=aw;
    ((float4*)(h + r0*64))[t] = o;
}

__global__ __launch_bounds__(512)
void k_agg(const float* __restrict__ h, const int* __restrict__ idxl,
           const float* __restrict__ wgtl, const float* __restrict__ bias,
           float* __restrict__ out) {
    __shared__ float4 hs4[512*16];   // 128KB: h[b] staged
    __shared__ uint2  iw[32*80];     // 20KB: (idx, weight) pairs for 32 targets
    int chunk = blockIdx.x, b = blockIdx.y, t = threadIdx.x;
    const float4* hb = (const float4*)h + b*8192;
    for (int e = t; e < 8192; e += 512) hs4[e] = hb[e];
    int lane = t & 63, wv = t >> 6;
    int ts = lane >> 4, fq = lane & 15;
    int tl = wv*4 + ts;              // local target 0..31
    float4 bv = ((const float4*)bias)[fq];
    int i0 = chunk*64;
    for (int grp = 0; grp < 2; ++grp) {
        int tbase = i0 + grp*32;
        int ti = tbase + tl;
        float ax=0, ay=0, az=0, aw=0;
        for (int ph = 0; ph < 2; ++ph) {
            int k0 = ph*80;
            __syncthreads();         // protect iw overwrite vs prior reads
            for (int e = t; e < 32*80; e += 512) {
                int l = e/80, kk = e%80; int kg = k0 + kk;
                uint2 v;
                if (kg < TOPK) {
                    v.x = (unsigned)idxl[(tbase+l)*KP + kg];
                    v.y = __float_as_uint(wgtl[(tbase+l)*KP + kg]);
                } else { v.x = 0u; v.y = 0u; }   // zero-weight pad
                iw[e] = v;
            }
            __syncthreads();
            const uint2* ip = &iw[tl*80];
            #pragma unroll 4
            for (int kk = 0; kk < 80; ++kk) {
                uint2 p = ip[kk];
                float w = __uint_as_float(p.y);
                float4 hv = hs4[p.x*16 + fq];
                ax += w*hv.x; ay += w*hv.y; az += w*hv.z; aw += w*hv.w;
            }
        }
        float4 o; o.x = ax+bv.x; o.y = ay+bv.y; o.z = az+bv.z; o.w = aw+bv.w;
        ((float4*)out)[(b*512 + ti)*16 + fq] = o;
    }
}

extern "C" void kernel_launch(void* const* d_in, const int* in_sizes, int n_in,
                              void* d_out, int out_size, void* d_ws, size_t ws_size,
                              hipStream_t stream) {
    const float* x    = (const float*)d_in[0];   // [32,512,64]
    const float* W    = (const float*)d_in[1];   // [64,64]
    const float* bias = (const float*)d_in[2];   // [64]
    const float* emb  = (const float*)d_in[3];   // [512,64]
    float* out = (float*)d_out;

    char* ws = (char*)d_ws;
    float* cosm  = (float*)(ws + 0x000000);      // aliased: common after topk
    unsigned long long* G  = (unsigned long long*)(ws + 0x100000);
    unsigned long long* nbm = (unsigned long long*)(ws + 0x108000);
    int*   idxl  = (int*)(ws + 0x110000);
    float* wgtl  = (float*)(ws + 0x160000);
    float* dinv  = (float*)(ws + 0x1B0000);
    float* norms = (float*)(ws + 0x1B0800);
    int*   maxc  = (int*)(ws + 0x1B1000);
    float* h     = (float*)(ws + 0x1C0000);
    float* common = cosm;

    k_norms<<<1, 512, 0, stream>>>(emb, norms, maxc);
    k_cos<<<N, 256, 0, stream>>>(emb, norms, cosm);
    k_topk<<<N, 256, 0, stream>>>(cosm, idxl, G);
    k_nb<<<16, 256, 0, stream>>>(G, nbm);
    k_common<<<N, 256, 0, stream>>>(nbm, common, maxc);
    k_ew<<<N, 256, 0, stream>>>(common, idxl, maxc, wgtl, dinv);
    k_wgt2<<<320, 256, 0, stream>>>(idxl, dinv, wgtl);
    k_h<<<BN/16, 256, 0, stream>>>(x, W, h);
    k_agg<<<dim3(8, NB), 512, 0, stream>>>(h, idxl, wgtl, bias, out);
}